// Round 1
// baseline (1103.769 us; speedup 1.0000x reference)
//
#include <hip/hip_runtime.h>

#define L_A 128
#define B_DIM 64
#define NUM_RULES 256
#define NUM_TOKENS 32000
#define MAX_QUERY 512
#define N_ELEMS (L_A * B_DIM)   // 8192
#define EPS 1e-7f

__global__ __launch_bounds__(256) void loss_kernel(
    const float* __restrict__ rule_prob,   // (L_A, B, NUM_RULES)
    const float* __restrict__ token_prob,  // (L_A, B, NUM_TOKENS)
    const float* __restrict__ copy_prob,   // (L_A, B, MAX_QUERY)
    const int*   __restrict__ gt_rule,     // (L_A, B)
    const int*   __restrict__ gt_token,    // (L_A, B)
    const int*   __restrict__ gt_copy,     // (L_A, B)
    const float* __restrict__ mask,        // (L_A, B)
    float*       __restrict__ out)         // scalar
{
    const int i = blockIdx.x * blockDim.x + threadIdx.x;  // 0..8191, i = l*B + b

    float loss = 0.0f;
    if (i < N_ELEMS) {
        const int r = gt_rule[i];
        const int t = gt_token[i];
        const int c = gt_copy[i];

        float p = 0.0f;
        if (r != -1) p += rule_prob[(size_t)i * NUM_RULES + r];
        if (t != -1) p += token_prob[(size_t)i * NUM_TOKENS + t];
        if (c != -1) p += copy_prob[(size_t)i * MAX_QUERY + c];

        // reference: prob = prob + (prob < EPS) * EPS  (NOT a clamp)
        if (p < EPS) p += EPS;

        loss = -logf(p) * mask[i];
    }

    // wave-64 shuffle reduction
    #pragma unroll
    for (int off = 32; off > 0; off >>= 1)
        loss += __shfl_down(loss, off, 64);

    __shared__ float s_wave[4];  // 256 threads = 4 waves
    const int lane = threadIdx.x & 63;
    const int wave = threadIdx.x >> 6;
    if (lane == 0) s_wave[wave] = loss;
    __syncthreads();

    if (threadIdx.x == 0) {
        const float blk = s_wave[0] + s_wave[1] + s_wave[2] + s_wave[3];
        // final result = (1/B) * sum over all (l,b)
        atomicAdd(out, blk * (1.0f / B_DIM));
    }
}

extern "C" void kernel_launch(void* const* d_in, const int* in_sizes, int n_in,
                              void* d_out, int out_size, void* d_ws, size_t ws_size,
                              hipStream_t stream) {
    const float* rule_prob  = (const float*)d_in[0];
    const float* token_prob = (const float*)d_in[1];
    const float* copy_prob  = (const float*)d_in[2];
    const int*   gt_rule    = (const int*)d_in[3];
    const int*   gt_token   = (const int*)d_in[4];
    const int*   gt_copy    = (const int*)d_in[5];
    const float* mask       = (const float*)d_in[6];
    float*       out        = (float*)d_out;

    // d_out is poisoned to 0xAA before every call; we accumulate via atomics,
    // so zero it first (hipMemsetAsync is graph-capture safe).
    hipMemsetAsync(out, 0, sizeof(float), stream);

    loss_kernel<<<N_ELEMS / 256, 256, 0, stream>>>(
        rule_prob, token_prob, copy_prob, gt_rule, gt_token, gt_copy, mask, out);
}